// Round 17
// baseline (180.711 us; speedup 1.0000x reference)
//
#include <hip/hip_runtime.h>

#define BATCH   16384
#define HIDDEN  1024
#define K2      2048     // x | h_prev   (h_mem folded into MQ gather)
#define MEMSZ   1024
#define NBITS   10

#define BM 256
#define BN 256
#define BK 64
#define NT (K2 / BK)     // 32 K-tiles

// front-kernel families: mq (split-K) | build | stream
#define MQB     256                 // mq: 4 ksplits x 8x8 tiles of 128x128
#define BBLK    2048                // build: 2 rows/wave * 4 waves
#define U_BM    262144              // Bm units (8-elem): 1024*2048/8
#define U_TOT   2359296             // + x units: 16384*1024/8
#define SBLK    2304                // stream blocks: 2304*256*4 = 2359296
#define SSTRIDE (SBLK * 256)

typedef __bf16 bf16x8 __attribute__((ext_vector_type(8)));
typedef float  f32x4  __attribute__((ext_vector_type(4)));
typedef unsigned short u16x8 __attribute__((ext_vector_type(8)));

__device__ __forceinline__ unsigned short f2bf(float f) {
    unsigned int u = __float_as_uint(f);
    u += 0x7FFFu + ((u >> 16) & 1u);   // round-to-nearest-even
    return (unsigned short)(u >> 16);
}

__device__ __forceinline__ u16x8 f2bf8(float4 a, float4 b) {
    u16x8 r;
    r[0] = f2bf(a.x); r[1] = f2bf(a.y); r[2] = f2bf(a.z); r[3] = f2bf(a.w);
    r[4] = f2bf(b.x); r[5] = f2bf(b.y); r[6] = f2bf(b.z); r[7] = f2bf(b.w);
    return r;
}

__device__ __forceinline__ ushort4 f2bf4(float4 a) {
    ushort4 r;
    r.x = f2bf(a.x); r.y = f2bf(a.y); r.z = f2bf(a.z); r.w = f2bf(a.w);
    return r;
}

__device__ __forceinline__ void gload_lds16(const void* g, void* l) {
    __builtin_amdgcn_global_load_lds(
        (const __attribute__((address_space(1))) unsigned int*)g,
        (__attribute__((address_space(3))) unsigned int*)l,
        16, 0, 0);
}

// ---------------------------------------------------------------------------
// FRONT v4: three families, resource-decoupled (R14's failure was 40KB LDS +
// 144 VGPR on every block; now LDS=16KB (mq only), VGPR ~= mq's ~128):
//  [0, 256):        mq split-K x4 — MQ += bf16(memory)@bf16(Q)^T slice.
//                   Serial chains start first, hide under stream traffic.
//                   atomicAdd onto memset-zeroed MQ (only ln consumes MQ).
//  [256, 2304):     build — 2 rows/wave; M_w from L2; conflict-free c4;
//                   fp32 logits; idx[row]; A[:,1024:2048] = bf16(h_prev).
//  [2304, 4608):    stream — Bm = bf16([W|U]); A[:,0:1024] = bf16(x).
// ---------------------------------------------------------------------------
__global__ __launch_bounds__(256) void front_kernel(
        const float* __restrict__ W, const float* __restrict__ U,
        const float* __restrict__ x, const float* __restrict__ h_prev,
        const float* __restrict__ memory, const float* __restrict__ Q,
        const float* __restrict__ M_w, const float* __restrict__ M_b,
        unsigned short* __restrict__ Bm, unsigned short* __restrict__ A,
        float* __restrict__ MQ, int* __restrict__ idxbuf) {
    __shared__ alignas(16) char shmem[16384];   // mq family only

    if (blockIdx.x < MQB) {
        // ---------------- mq family (split-K x4, R15/R16-proven) -----------
        unsigned short* As = reinterpret_cast<unsigned short*>(shmem);         // 8 KB
        unsigned short* Bs = reinterpret_cast<unsigned short*>(shmem + 8192);  // 8 KB

        const int ks = blockIdx.x >> 6;       // 0..3 K-split
        const int mb = (blockIdx.x >> 3) & 7;
        const int nb = blockIdx.x & 7;
        const int t    = threadIdx.x;
        const int lane = t & 63;
        const int w    = t >> 6;
        const int wr   = w >> 1, wc = w & 1;
        const int rr   = lane & 15, rq = lane >> 4;
        const int srow = t >> 1;              // 0..127
        const int scol = (t & 1) * 16;        // elem col base (0/16)
        const int swr  = (srow & 3) << 4;     // write swizzle

        f32x4 acc[4][4] = {};

        for (int kt = 0; kt < 8; ++kt) {
            const int k0 = ks * 256 + kt * 32;
            const float* ap = memory + (size_t)(mb * 128 + srow) * 1024 + k0 + scol;
            const float* bp = Q      + (size_t)(nb * 128 + srow) * 1024 + k0 + scol;
            float4 a0 = *reinterpret_cast<const float4*>(ap);
            float4 a1 = *reinterpret_cast<const float4*>(ap + 4);
            float4 a2 = *reinterpret_cast<const float4*>(ap + 8);
            float4 a3 = *reinterpret_cast<const float4*>(ap + 12);
            float4 b0 = *reinterpret_cast<const float4*>(bp);
            float4 b1 = *reinterpret_cast<const float4*>(bp + 4);
            float4 b2 = *reinterpret_cast<const float4*>(bp + 8);
            float4 b3 = *reinterpret_cast<const float4*>(bp + 12);
            __syncthreads();   // previous iter's reads complete before overwrite
            {
                char* ar = reinterpret_cast<char*>(As) + srow * 64;
                char* br = reinterpret_cast<char*>(Bs) + srow * 64;
                *reinterpret_cast<u16x8*>(ar + ((scol * 2)      ^ swr)) = f2bf8(a0, a1);
                *reinterpret_cast<u16x8*>(ar + ((scol * 2 + 16) ^ swr)) = f2bf8(a2, a3);
                *reinterpret_cast<u16x8*>(br + ((scol * 2)      ^ swr)) = f2bf8(b0, b1);
                *reinterpret_cast<u16x8*>(br + ((scol * 2 + 16) ^ swr)) = f2bf8(b2, b3);
            }
            __syncthreads();
            bf16x8 af[4], bfv[4];
#pragma unroll
            for (int m = 0; m < 4; ++m) {
                int r = wr * 64 + m * 16 + rr;
                af[m] = *reinterpret_cast<const bf16x8*>(
                    reinterpret_cast<const char*>(As) + r * 64 + ((rq * 16) ^ ((r & 3) << 4)));
            }
#pragma unroll
            for (int n = 0; n < 4; ++n) {
                int r = wc * 64 + n * 16 + rr;
                bfv[n] = *reinterpret_cast<const bf16x8*>(
                    reinterpret_cast<const char*>(Bs) + r * 64 + ((rq * 16) ^ ((r & 3) << 4)));
            }
#pragma unroll
            for (int m = 0; m < 4; ++m)
#pragma unroll
                for (int n = 0; n < 4; ++n)
                    acc[m][n] = __builtin_amdgcn_mfma_f32_16x16x32_bf16(
                        af[m], bfv[n], acc[m][n], 0, 0, 0);
        }

#pragma unroll
        for (int m = 0; m < 4; ++m)
#pragma unroll
            for (int n = 0; n < 4; ++n) {
                int gcol = nb * 128 + wc * 64 + n * 16 + rr;
#pragma unroll
                for (int j = 0; j < 4; ++j) {
                    int grow = mb * 128 + wr * 64 + m * 16 + rq * 4 + j;
                    atomicAdd(&MQ[(size_t)grow * 1024 + gcol], acc[m][n][j]);
                }
            }
        return;
    }

    if (blockIdx.x < MQB + BBLK) {
        // ---------------- build family (R15-proven) ------------------------
        const int wv   = threadIdx.x >> 6;
        const int lane = threadIdx.x & 63;
        const int row0 = ((blockIdx.x - MQB) * 4 + wv) * 2;
        const int c4   = lane * 4;

        float4 h[2][4];
#pragma unroll
        for (int r = 0; r < 2; ++r) {
            const float* hr = h_prev + (size_t)(row0 + r) * HIDDEN;
#pragma unroll
            for (int seg = 0; seg < 4; ++seg)
                h[r][seg] = *reinterpret_cast<const float4*>(hr + seg * 256 + c4);
        }

        float s[2][NBITS];
#pragma unroll
        for (int j = 0; j < NBITS; ++j) {
            const float* mj = M_w + (size_t)j * HIDDEN;
            float4 m[4];
#pragma unroll
            for (int seg = 0; seg < 4; ++seg)
                m[seg] = *reinterpret_cast<const float4*>(mj + seg * 256 + c4);
#pragma unroll
            for (int r = 0; r < 2; ++r) {
                float acc = 0.f;
#pragma unroll
                for (int seg = 0; seg < 4; ++seg)
                    acc += h[r][seg].x * m[seg].x + h[r][seg].y * m[seg].y
                         + h[r][seg].z * m[seg].z + h[r][seg].w * m[seg].w;
                s[r][j] = acc;
            }
        }
#pragma unroll
        for (int off = 32; off >= 1; off >>= 1) {
#pragma unroll
            for (int r = 0; r < 2; ++r)
#pragma unroll
                for (int j = 0; j < NBITS; ++j)
                    s[r][j] += __shfl_xor(s[r][j], off, 64);
        }
#pragma unroll
        for (int r = 0; r < 2; ++r) {
            int idx = 0;
#pragma unroll
            for (int j = 0; j < NBITS; ++j)
                if (s[r][j] + M_b[j] > 0.f) idx |= 1 << (NBITS - 1 - j);
            if (lane == 0) idxbuf[row0 + r] = idx;
        }

#pragma unroll
        for (int r = 0; r < 2; ++r) {
            unsigned short* arow = A + (size_t)(row0 + r) * K2 + 1024;
#pragma unroll
            for (int seg = 0; seg < 4; ++seg)
                *reinterpret_cast<ushort4*>(arow + seg * 256 + c4) = f2bf4(h[r][seg]);
        }
        return;
    }

    // ---------------- stream family (R15-proven) ----------------------------
    const int u0 = (blockIdx.x - MQB - BBLK) * 256 + threadIdx.x;
    const float* s4[4];
    unsigned short* d4[4];
#pragma unroll
    for (int i = 0; i < 4; ++i) {
        int u = u0 + i * SSTRIDE;
        if (u < U_BM) {                        // Bm: 1024 x 2048
            int n  = u >> 8;
            int k8 = (u & 255) << 3;
            s4[i] = (k8 < 1024) ? (W + (size_t)n * 1024 + k8)
                                : (U + (size_t)n * 1024 + (k8 - 1024));
            d4[i] = Bm + (size_t)n * K2 + k8;
        } else {                               // x -> A[:, 0:1024]
            int e = (u - U_BM) << 3;
            int row = e >> 10, col = e & 1023;
            s4[i] = x + (size_t)row * HIDDEN + col;
            d4[i] = A + (size_t)row * K2 + col;
        }
    }
    float4 va[4], vb[4];
#pragma unroll
    for (int i = 0; i < 4; ++i) {
        va[i] = *reinterpret_cast<const float4*>(s4[i]);
        vb[i] = *reinterpret_cast<const float4*>(s4[i] + 4);
    }
    __builtin_amdgcn_sched_barrier(0);   // all 8 loads in flight first
#pragma unroll
    for (int i = 0; i < 4; ++i)
        *reinterpret_cast<u16x8*>(d4[i]) = f2bf8(va[i], vb[i]);
}

// ---------------------------------------------------------------------------
// 256x256-tile GEMM, rotated schedule, one barrier per phase (frozen, R11).
// ---------------------------------------------------------------------------

__device__ __forceinline__ void stage_g(const unsigned short* __restrict__ src,
                                        int rowbase, int kt, int g,
                                        unsigned short* ldsTile, int t) {
    const int o      = g * 8192 + t * 16;     // byte offset within 32 KB tile
    const int row    = o >> 7;                // 0..255  (128 B per row)
    const int inner  = o & 127;
    const int sinner = inner ^ ((row & 7) << 4);
    const char* gp = reinterpret_cast<const char*>(
                         src + (size_t)(rowbase + row) * K2 + kt * BK) + sinner;
    gload_lds16(gp, reinterpret_cast<char*>(ldsTile) + o);
}

__device__ __forceinline__ bf16x8 ldsfrag(const unsigned short* tile, int row,
                                          int kbyte_x_sw) {
    return *reinterpret_cast<const bf16x8*>(
        reinterpret_cast<const char*>(tile) + row * 128 + kbyte_x_sw);
}

#define PH_BAR()                                                     \
    do {                                                             \
        asm volatile("" ::: "memory");                               \
        __builtin_amdgcn_s_barrier();                                \
        asm volatile("" ::: "memory");                               \
    } while (0)

#define LGKM(N)                                                      \
    do {                                                             \
        asm volatile("s_waitcnt lgkmcnt(" #N ")" ::: "memory");      \
        __builtin_amdgcn_sched_barrier(0);                           \
    } while (0)

#define MFMA_Q(AF, BF, MB, NB)                                                 \
    {                                                                          \
        __builtin_amdgcn_s_setprio(1);                                         \
        _Pragma("unroll") for (int m_ = 0; m_ < 4; ++m_)                       \
        _Pragma("unroll") for (int n_ = 0; n_ < 2; ++n_)                       \
        _Pragma("unroll") for (int kk_ = 0; kk_ < 2; ++kk_)                    \
            acc[(MB) + m_][(NB) + n_] =                                        \
                __builtin_amdgcn_mfma_f32_16x16x32_bf16(                       \
                    AF[m_][kk_], BF[n_][kk_],                                  \
                    acc[(MB) + m_][(NB) + n_], 0, 0, 0);                       \
        __builtin_amdgcn_s_setprio(0);                                         \
    }

__global__ __launch_bounds__(512, 2) void gemm_kernel(
        const unsigned short* __restrict__ A,
        const unsigned short* __restrict__ Bm,
        float* __restrict__ C) {
    __shared__ alignas(16) unsigned short lds[2][2][BM * BK];  // 128 KiB

    const int bid  = blockIdx.x;
    const int wgid = (bid & 7) * 32 + (bid >> 3);
    const int mblk = wgid >> 2;           // 0..63
    const int nblk = wgid & 3;            // 0..3

    const int t    = threadIdx.x;
    const int lane = t & 63;
    const int w    = t >> 6;
    const int wr   = w >> 2;              // 0..1  (M)
    const int wc   = w & 3;               // 0..3  (N)
    const int rr   = lane & 15;
    const int rq   = lane >> 4;
    const int sw   = (rr & 7) << 4;
    const int rqb  = rq * 16;
    const int wrb  = wr * 128;
    const int wcb  = wc * 64;

    const int arow = mblk * BM;
    const int brow = nblk * BN;

    f32x4 acc[8][4] = {};

    {
#pragma unroll
        for (int g = 0; g < 4; ++g) stage_g(A,  arow, 0, g, &lds[0][0][0], t);
#pragma unroll
        for (int g = 0; g < 4; ++g) stage_g(Bm, brow, 0, g, &lds[0][1][0], t);
#pragma unroll
        for (int g = 0; g < 4; ++g) stage_g(Bm, brow, 1, g, &lds[1][1][0], t);
#pragma unroll
        for (int g = 0; g < 4; ++g) stage_g(A,  arow, 1, g, &lds[1][0][0], t);
        asm volatile("s_waitcnt vmcnt(8)" ::: "memory");   // tile0 landed
        asm volatile("" ::: "memory");
        __builtin_amdgcn_s_barrier();
    }

    bf16x8 af  [4][2];   // A rows 0-63 of wave slab
    bf16x8 af2 [4][2];   // A rows 64-127 of wave slab
    bf16x8 bfr01[2][2];  // B cols wcb+0..31
    bf16x8 bfr23[2][2];  // B cols wcb+32..63

#pragma unroll
    for (int m = 0; m < 4; ++m) {
        af[m][0] = ldsfrag(&lds[0][0][0], wrb + m * 16 + rr, (rqb) ^ sw);
        af[m][1] = ldsfrag(&lds[0][0][0], wrb + m * 16 + rr, (64 + rqb) ^ sw);
    }
#pragma unroll
    for (int n = 0; n < 2; ++n) {
        bfr01[n][0] = ldsfrag(&lds[0][1][0], wcb + n * 16 + rr, (rqb) ^ sw);
        bfr01[n][1] = ldsfrag(&lds[0][1][0], wcb + n * 16 + rr, (64 + rqb) ^ sw);
    }

    for (int kt = 0; kt < NT; ++kt) {
        const int c = kt & 1;
        const unsigned short* At  = &lds[c][0][0];
        const unsigned short* Bt  = &lds[c][1][0];
        const unsigned short* nxA = &lds[c ^ 1][0][0];  // tile kt+1
        const unsigned short* nxB = &lds[c ^ 1][1][0];
        unsigned short* curA = &lds[c][0][0];           // tile kt+2 targets
        unsigned short* curB = &lds[c][1][0];
        const bool pf1 = (kt + 1 < NT);
        const bool pf2 = (kt + 2 < NT);

        // -- ph0: read b23(cur) + af2[0] (6); MFMA af x b01 ------------------
        PH_BAR();
#pragma unroll
        for (int n = 0; n < 2; ++n) {
            bfr23[n][0] = ldsfrag(Bt, wcb + 32 + n * 16 + rr, (rqb) ^ sw);
            bfr23[n][1] = ldsfrag(Bt, wcb + 32 + n * 16 + rr, (64 + rqb) ^ sw);
        }
        af2[0][0] = ldsfrag(At, wrb + 64 + rr, (rqb) ^ sw);
        af2[0][1] = ldsfrag(At, wrb + 64 + rr, (64 + rqb) ^ sw);
        LGKM(6);
        MFMA_Q(af, bfr01, 0, 0);

        // -- ph1: read af2[1-3] (6); MFMA af x b23; drain stages -------------
        PH_BAR();
#pragma unroll
        for (int m = 1; m < 4; ++m) {
            af2[m][0] = ldsfrag(At, wrb + 64 + m * 16 + rr, (rqb) ^ sw);
            af2[m][1] = ldsfrag(At, wrb + 64 + m * 16 + rr, (64 + rqb) ^ sw);
        }
        LGKM(8);
        MFMA_Q(af, bfr23, 0, 2);
        __builtin_amdgcn_sched_barrier(0);
        asm volatile("s_waitcnt vmcnt(0)" ::: "memory");  // tile kt+1 landed
        asm volatile("" ::: "memory");

        // -- ph2: stage B(kt+2); read af(kt+1)[0-2] (6); MFMA af2 x b01 ------
        PH_BAR();
        if (pf2) {
            stage_g(Bm, brow, kt + 2, 0, curB, t);
            stage_g(Bm, brow, kt + 2, 1, curB, t);
            stage_g(Bm, brow, kt + 2, 2, curB, t);
            stage_g(Bm, brow, kt + 2, 3, curB, t);
        }
        if (pf1) {
#pragma unroll
            for (int m = 0; m < 3; ++m) {
                af[m][0] = ldsfrag(nxA, wrb + m * 16 + rr, (rqb) ^ sw);
                af[m][1] = ldsfrag(nxA, wrb + m * 16 + rr, (64 + rqb) ^ sw);
            }
            LGKM(6);
        } else {
            LGKM(0);
        }
        MFMA_Q(af2, bfr01, 4, 0);

        // -- ph3: stage A(kt+2); read af[3] + b01(kt+1) (6); MFMA af2 x b23 --
        PH_BAR();
        if (pf2) {
            stage_g(A, arow, kt + 2, 0, curA, t);
            stage_g(A, arow, kt + 2, 1, curA, t);
            stage_g(A, arow, kt + 2, 2, curA, t);
            stage_g(A, arow, kt + 2, 3, curA, t);
        }
        if (pf1) {
            af[3][0] = ldsfrag(nxA, wrb + 48 + rr, (rqb) ^ sw);
            af[3][1] = ldsfrag(nxA, wrb + 48 + rr, (64 + rqb) ^ sw);
#pragma unroll
            for (int n = 0; n < 2; ++n) {
                bfr01[n][0] = ldsfrag(nxB, wcb + n * 16 + rr, (rqb) ^ sw);
                bfr01[n][1] = ldsfrag(nxB, wcb + n * 16 + rr, (64 + rqb) ^ sw);
            }
        }
        MFMA_Q(af2, bfr23, 4, 2);
    }

#pragma unroll
    for (int mi = 0; mi < 8; ++mi) {
#pragma unroll
        for (int n = 0; n < 4; ++n) {
            const int gcol = nblk * BN + wcb + n * 16 + rr;
#pragma unroll
            for (int j = 0; j < 4; ++j) {
                const int grow = mblk * BM + wrb + mi * 16 + rq * 4 + j;
                C[(size_t)grow * HIDDEN + gcol] = acc[mi][n][j];
            }
        }
    }
}

// ---------------------------------------------------------------------------
// In-place: p = C + MQ[idx[row]] + (W_b+U_b+Q_b); LayerNorm; sigmoid (R11).
// ---------------------------------------------------------------------------
__global__ __launch_bounds__(256) void ln_kernel(
        float* __restrict__ C,
        const int* __restrict__ idxbuf,
        const float* __restrict__ MQ,
        const float* __restrict__ W_b, const float* __restrict__ U_b,
        const float* __restrict__ Q_b, const float* __restrict__ ln_g,
        const float* __restrict__ ln_b) {
    const int row = blockIdx.x;
    const int t   = threadIdx.x;
    const int midx = idxbuf[row];
    float4* rowp = reinterpret_cast<float4*>(C + (size_t)row * HIDDEN);
    const float4* mqp = reinterpret_cast<const float4*>(MQ + (size_t)midx * HIDDEN);

    float4 p  = rowp[t];
    float4 mq = mqp[t];
    float4 bw = reinterpret_cast<const float4*>(W_b)[t];
    float4 bu = reinterpret_cast<const float4*>(U_b)[t];
    float4 bq = reinterpret_cast<const float4*>(Q_b)[t];
    p.x += mq.x + bw.x + bu.x + bq.x;
    p.y += mq.y + bw.y + bu.y + bq.y;
    p.z += mq.z + bw.z + bu.z + bq.z;
    p.w += mq.w + bw.w + bu.w + bq.w;

    float s  = p.x + p.y + p.z + p.w;
    float sq = p.x * p.x + p.y * p.y + p.z * p.z + p.w * p.w;
#pragma unroll
    for (int off = 32; off >= 1; off >>= 1) {
        s  += __shfl_xor(s,  off, 64);
        sq += __shfl_xor(sq, off, 64);
    }
    __shared__ float red[8];
    const int lane = t & 63, w = t >> 6;
    if (lane == 0) { red[w] = s; red[4 + w] = sq; }
    __syncthreads();
    const float S    = red[0] + red[1] + red[2] + red[3];
    const float SQ   = red[4] + red[5] + red[6] + red[7];
    const float mean = S * (1.0f / HIDDEN);
    const float var  = SQ * (1.0f / HIDDEN) - mean * mean;
    const float rstd = rsqrtf(var + 1e-5f);

    float4 g = reinterpret_cast<const float4*>(ln_g)[t];
    float4 b = reinterpret_cast<const float4*>(ln_b)[t];
    float4 o;
    o.x = 1.f / (1.f + __expf(-((p.x - mean) * rstd * g.x + b.x)));
    o.y = 1.f / (1.f + __expf(-((p.y - mean) * rstd * g.y + b.y)));
    o.z = 1.f / (1.f + __expf(-((p.z - mean) * rstd * g.z + b.z)));
    o.w = 1.f / (1.f + __expf(-((p.w - mean) * rstd * g.w + b.w)));
    rowp[t] = o;
}

// ---------------------------------------------------------------------------
extern "C" void kernel_launch(void* const* d_in, const int* in_sizes, int n_in,
                              void* d_out, int out_size, void* d_ws, size_t ws_size,
                              hipStream_t stream) {
    const float* x      = (const float*)d_in[0];
    const float* h_prev = (const float*)d_in[1];
    const float* memory = (const float*)d_in[2];
    const float* W_w    = (const float*)d_in[3];
    const float* W_b    = (const float*)d_in[4];
    const float* U_w    = (const float*)d_in[5];
    const float* U_b    = (const float*)d_in[6];
    const float* Q_w    = (const float*)d_in[7];
    const float* Q_b    = (const float*)d_in[8];
    const float* M_w    = (const float*)d_in[9];
    const float* M_b    = (const float*)d_in[10];
    const float* ln_g   = (const float*)d_in[11];
    const float* ln_b   = (const float*)d_in[12];

    // ws layout (bytes):
    char* ws = (char*)d_ws;
    unsigned short* A   = (unsigned short*)(ws);                 // 67,108,864
    unsigned short* Bm  = (unsigned short*)(ws + 67108864);      //  4,194,304
    float*          MQ  = (float*)         (ws + 71303168);      //  4,194,304
    int*            idx = (int*)           (ws + 75497472);      //     65,536

    float* pre = (float*)d_out;

    hipMemsetAsync(MQ, 0, (size_t)MEMSZ * HIDDEN * sizeof(float), stream);
    hipLaunchKernelGGL(front_kernel, dim3(MQB + BBLK + SBLK), dim3(256), 0, stream,
                       W_w, U_w, x, h_prev, memory, Q_w, M_w, M_b,
                       Bm, A, MQ, idx);
    hipLaunchKernelGGL(gemm_kernel, dim3((BATCH / BM) * (HIDDEN / BN)), dim3(512), 0, stream,
                       A, Bm, pre);
    hipLaunchKernelGGL(ln_kernel, dim3(BATCH), dim3(256), 0, stream,
                       pre, idx, MQ, W_b, U_b, Q_b, ln_g, ln_b);
}

// Round 18
// 159.961 us; speedup vs baseline: 1.1297x; 1.1297x over previous
//
#include <hip/hip_runtime.h>

#define BATCH   16384
#define HIDDEN  1024
#define K2      2048     // x | h_prev   (h_mem folded into MQ gather)
#define MEMSZ   1024
#define NBITS   10

#define BM 256
#define BN 256
#define BK 64
#define NT (K2 / BK)     // 32 K-tiles

#define MQB     256                 // mq family blocks inside gemm kernel
// front-kernel geometry: build blocks first, then stream blocks
#define BBLK    2048                // build: 2 rows/wave * 4 waves
#define U_BM    262144              // Bm units (8-elem): 1024*2048/8
#define U_TOT   2359296             // + x units: 16384*1024/8
#define SBLK    2304                // stream blocks: 2304*256*4 = 2359296
#define SSTRIDE (SBLK * 256)

typedef __bf16 bf16x8 __attribute__((ext_vector_type(8)));
typedef float  f32x4  __attribute__((ext_vector_type(4)));
typedef unsigned short u16x8 __attribute__((ext_vector_type(8)));

__device__ __forceinline__ unsigned short f2bf(float f) {
    unsigned int u = __float_as_uint(f);
    u += 0x7FFFu + ((u >> 16) & 1u);   // round-to-nearest-even
    return (unsigned short)(u >> 16);
}

__device__ __forceinline__ u16x8 f2bf8(float4 a, float4 b) {
    u16x8 r;
    r[0] = f2bf(a.x); r[1] = f2bf(a.y); r[2] = f2bf(a.z); r[3] = f2bf(a.w);
    r[4] = f2bf(b.x); r[5] = f2bf(b.y); r[6] = f2bf(b.z); r[7] = f2bf(b.w);
    return r;
}

__device__ __forceinline__ ushort4 f2bf4(float4 a) {
    ushort4 r;
    r.x = f2bf(a.x); r.y = f2bf(a.y); r.z = f2bf(a.z); r.w = f2bf(a.w);
    return r;
}

__device__ __forceinline__ void gload_lds16(const void* g, void* l) {
    __builtin_amdgcn_global_load_lds(
        (const __attribute__((address_space(1))) unsigned int*)g,
        (__attribute__((address_space(3))) unsigned int*)l,
        16, 0, 0);
}

// ---------------------------------------------------------------------------
// FRONT (R16 form, frozen at 66 us / 0 conflicts / VGPR 88):
//  [0, 2048):      build — 2 rows/wave; M_w from L2; conflict-free c4;
//                  fp32 logits; idx[row]; A[:,1024:2048] = bf16(h_prev).
//  [2048, +2304):  stream — Bm = bf16([W|U]); A[:,0:1024] = bf16(x).
// ---------------------------------------------------------------------------
__global__ __launch_bounds__(256) void front_kernel(
        const float* __restrict__ W, const float* __restrict__ U,
        const float* __restrict__ x, const float* __restrict__ h_prev,
        const float* __restrict__ M_w, const float* __restrict__ M_b,
        unsigned short* __restrict__ Bm, unsigned short* __restrict__ A,
        int* __restrict__ idxbuf) {
    if (blockIdx.x < BBLK) {
        const int wv   = threadIdx.x >> 6;
        const int lane = threadIdx.x & 63;
        const int row0 = (blockIdx.x * 4 + wv) * 2;
        const int c4   = lane * 4;

        float4 h[2][4];
#pragma unroll
        for (int r = 0; r < 2; ++r) {
            const float* hr = h_prev + (size_t)(row0 + r) * HIDDEN;
#pragma unroll
            for (int seg = 0; seg < 4; ++seg)
                h[r][seg] = *reinterpret_cast<const float4*>(hr + seg * 256 + c4);
        }

        float s[2][NBITS];
#pragma unroll
        for (int j = 0; j < NBITS; ++j) {
            const float* mj = M_w + (size_t)j * HIDDEN;
            float4 m[4];
#pragma unroll
            for (int seg = 0; seg < 4; ++seg)
                m[seg] = *reinterpret_cast<const float4*>(mj + seg * 256 + c4);
#pragma unroll
            for (int r = 0; r < 2; ++r) {
                float acc = 0.f;
#pragma unroll
                for (int seg = 0; seg < 4; ++seg)
                    acc += h[r][seg].x * m[seg].x + h[r][seg].y * m[seg].y
                         + h[r][seg].z * m[seg].z + h[r][seg].w * m[seg].w;
                s[r][j] = acc;
            }
        }
#pragma unroll
        for (int off = 32; off >= 1; off >>= 1) {
#pragma unroll
            for (int r = 0; r < 2; ++r)
#pragma unroll
                for (int j = 0; j < NBITS; ++j)
                    s[r][j] += __shfl_xor(s[r][j], off, 64);
        }
#pragma unroll
        for (int r = 0; r < 2; ++r) {
            int idx = 0;
#pragma unroll
            for (int j = 0; j < NBITS; ++j)
                if (s[r][j] + M_b[j] > 0.f) idx |= 1 << (NBITS - 1 - j);
            if (lane == 0) idxbuf[row0 + r] = idx;
        }

#pragma unroll
        for (int r = 0; r < 2; ++r) {
            unsigned short* arow = A + (size_t)(row0 + r) * K2 + 1024;
#pragma unroll
            for (int seg = 0; seg < 4; ++seg)
                *reinterpret_cast<ushort4*>(arow + seg * 256 + c4) = f2bf4(h[r][seg]);
        }
        return;
    }

    // ---------------- stream family -----------------------------------------
    const int u0 = (blockIdx.x - BBLK) * 256 + threadIdx.x;
    const float* s4[4];
    unsigned short* d4[4];
#pragma unroll
    for (int i = 0; i < 4; ++i) {
        int u = u0 + i * SSTRIDE;
        if (u < U_BM) {                        // Bm: 1024 x 2048
            int n  = u >> 8;
            int k8 = (u & 255) << 3;
            s4[i] = (k8 < 1024) ? (W + (size_t)n * 1024 + k8)
                                : (U + (size_t)n * 1024 + (k8 - 1024));
            d4[i] = Bm + (size_t)n * K2 + k8;
        } else {                               // x -> A[:, 0:1024]
            int e = (u - U_BM) << 3;
            int row = e >> 10, col = e & 1023;
            s4[i] = x + (size_t)row * HIDDEN + col;
            d4[i] = A + (size_t)row * K2 + col;
        }
    }
    float4 va[4], vb[4];
#pragma unroll
    for (int i = 0; i < 4; ++i) {
        va[i] = *reinterpret_cast<const float4*>(s4[i]);
        vb[i] = *reinterpret_cast<const float4*>(s4[i] + 4);
    }
    __builtin_amdgcn_sched_barrier(0);   // all 8 loads in flight first
#pragma unroll
    for (int i = 0; i < 4; ++i)
        *reinterpret_cast<u16x8*>(d4[i]) = f2bf8(va[i], vb[i]);
}

// ---------------------------------------------------------------------------
// GEMM + MQ merged kernel.
//  blocks [0, 256):    mq family (split-K x4, 512 threads, 8 waves of 64x32
//                      output): MQ += bf16(memory)@bf16(Q)^T slice via
//                      atomicAdd onto memset-zeroed MQ.  Uses 16 KB of the
//                      gemm's 128 KB LDS; VGPR <= gemm's 128 -> no resource
//                      coupling (the R14/R17 failure mode).  Dispatched
//                      first: one ~5 us wave across all CUs, then gemm.
//  blocks [256, 512):  256x256-tile GEMM, rotated schedule (frozen, R11).
// ---------------------------------------------------------------------------

__device__ __forceinline__ void stage_g(const unsigned short* __restrict__ src,
                                        int rowbase, int kt, int g,
                                        unsigned short* ldsTile, int t) {
    const int o      = g * 8192 + t * 16;     // byte offset within 32 KB tile
    const int row    = o >> 7;                // 0..255  (128 B per row)
    const int inner  = o & 127;
    const int sinner = inner ^ ((row & 7) << 4);
    const char* gp = reinterpret_cast<const char*>(
                         src + (size_t)(rowbase + row) * K2 + kt * BK) + sinner;
    gload_lds16(gp, reinterpret_cast<char*>(ldsTile) + o);
}

__device__ __forceinline__ bf16x8 ldsfrag(const unsigned short* tile, int row,
                                          int kbyte_x_sw) {
    return *reinterpret_cast<const bf16x8*>(
        reinterpret_cast<const char*>(tile) + row * 128 + kbyte_x_sw);
}

#define PH_BAR()                                                     \
    do {                                                             \
        asm volatile("" ::: "memory");                               \
        __builtin_amdgcn_s_barrier();                                \
        asm volatile("" ::: "memory");                               \
    } while (0)

#define LGKM(N)                                                      \
    do {                                                             \
        asm volatile("s_waitcnt lgkmcnt(" #N ")" ::: "memory");      \
        __builtin_amdgcn_sched_barrier(0);                           \
    } while (0)

#define MFMA_Q(AF, BF, MB, NB)                                                 \
    {                                                                          \
        __builtin_amdgcn_s_setprio(1);                                         \
        _Pragma("unroll") for (int m_ = 0; m_ < 4; ++m_)                       \
        _Pragma("unroll") for (int n_ = 0; n_ < 2; ++n_)                       \
        _Pragma("unroll") for (int kk_ = 0; kk_ < 2; ++kk_)                    \
            acc[(MB) + m_][(NB) + n_] =                                        \
                __builtin_amdgcn_mfma_f32_16x16x32_bf16(                       \
                    AF[m_][kk_], BF[n_][kk_],                                  \
                    acc[(MB) + m_][(NB) + n_], 0, 0, 0);                       \
        __builtin_amdgcn_s_setprio(0);                                         \
    }

__global__ __launch_bounds__(512, 2) void gemm_mq_kernel(
        const unsigned short* __restrict__ A,
        const unsigned short* __restrict__ Bm,
        const float* __restrict__ memory,
        const float* __restrict__ Q,
        float* __restrict__ MQ,
        float* __restrict__ C) {
    __shared__ alignas(16) unsigned short lds[2][2][BM * BK];  // 128 KiB

    const int bid = blockIdx.x;
    const int t   = threadIdx.x;

    if (bid < MQB) {
        // ---------------- mq family (512 threads, split-K x4) --------------
        unsigned short* As = &lds[0][0][0];           // 8 KB
        unsigned short* Bs = As + 128 * 32;           // 8 KB

        const int ks = bid >> 6;              // 0..3 K-split
        const int mb = (bid >> 3) & 7;
        const int nb = bid & 7;
        const int lane = t & 63;
        const int w    = t >> 6;              // 0..7
        const int wr   = w >> 2, wc = w & 3;  // 2x4 wave grid (64x32 out each)
        const int rr   = lane & 15, rq = lane >> 4;
        const int srow = t >> 2;              // 0..127
        const int sc8  = (t & 3) * 8;         // elem col base (0/8/16/24)
        const int swr  = (srow & 3) << 4;     // write swizzle

        f32x4 acc[4][2] = {};

        for (int kt = 0; kt < 8; ++kt) {
            const int k0 = ks * 256 + kt * 32;
            const float* ap = memory + (size_t)(mb * 128 + srow) * 1024 + k0 + sc8;
            const float* bp = Q      + (size_t)(nb * 128 + srow) * 1024 + k0 + sc8;
            float4 a0 = *reinterpret_cast<const float4*>(ap);
            float4 a1 = *reinterpret_cast<const float4*>(ap + 4);
            float4 b0 = *reinterpret_cast<const float4*>(bp);
            float4 b1 = *reinterpret_cast<const float4*>(bp + 4);
            __syncthreads();   // previous iter's reads done before overwrite
            {
                char* ar = reinterpret_cast<char*>(As) + srow * 64;
                char* br = reinterpret_cast<char*>(Bs) + srow * 64;
                *reinterpret_cast<u16x8*>(ar + ((sc8 * 2) ^ swr)) = f2bf8(a0, a1);
                *reinterpret_cast<u16x8*>(br + ((sc8 * 2) ^ swr)) = f2bf8(b0, b1);
            }
            __syncthreads();
            bf16x8 af[4], bfv[2];
#pragma unroll
            for (int m = 0; m < 4; ++m) {
                int r = wr * 64 + m * 16 + rr;
                af[m] = *reinterpret_cast<const bf16x8*>(
                    reinterpret_cast<const char*>(As) + r * 64 + ((rq * 16) ^ ((r & 3) << 4)));
            }
#pragma unroll
            for (int n = 0; n < 2; ++n) {
                int r = wc * 32 + n * 16 + rr;
                bfv[n] = *reinterpret_cast<const bf16x8*>(
                    reinterpret_cast<const char*>(Bs) + r * 64 + ((rq * 16) ^ ((r & 3) << 4)));
            }
#pragma unroll
            for (int m = 0; m < 4; ++m)
#pragma unroll
                for (int n = 0; n < 2; ++n)
                    acc[m][n] = __builtin_amdgcn_mfma_f32_16x16x32_bf16(
                        af[m], bfv[n], acc[m][n], 0, 0, 0);
        }

#pragma unroll
        for (int m = 0; m < 4; ++m)
#pragma unroll
            for (int n = 0; n < 2; ++n) {
                int gcol = nb * 128 + wc * 32 + n * 16 + rr;
#pragma unroll
                for (int j = 0; j < 4; ++j) {
                    int grow = mb * 128 + wr * 64 + m * 16 + rq * 4 + j;
                    atomicAdd(&MQ[(size_t)grow * 1024 + gcol], acc[m][n][j]);
                }
            }
        return;
    }

    // ---------------- gemm family (frozen R11 schedule) --------------------
    const int gbid = bid - MQB;
    const int wgid = (gbid & 7) * 32 + (gbid >> 3);
    const int mblk = wgid >> 2;           // 0..63
    const int nblk = wgid & 3;            // 0..3

    const int lane = t & 63;
    const int w    = t >> 6;
    const int wr   = w >> 2;              // 0..1  (M)
    const int wc   = w & 3;               // 0..3  (N)
    const int rr   = lane & 15;
    const int rq   = lane >> 4;
    const int sw   = (rr & 7) << 4;
    const int rqb  = rq * 16;
    const int wrb  = wr * 128;
    const int wcb  = wc * 64;

    const int arow = mblk * BM;
    const int brow = nblk * BN;

    f32x4 acc[8][4] = {};

    {
#pragma unroll
        for (int g = 0; g < 4; ++g) stage_g(A,  arow, 0, g, &lds[0][0][0], t);
#pragma unroll
        for (int g = 0; g < 4; ++g) stage_g(Bm, brow, 0, g, &lds[0][1][0], t);
#pragma unroll
        for (int g = 0; g < 4; ++g) stage_g(Bm, brow, 1, g, &lds[1][1][0], t);
#pragma unroll
        for (int g = 0; g < 4; ++g) stage_g(A,  arow, 1, g, &lds[1][0][0], t);
        asm volatile("s_waitcnt vmcnt(8)" ::: "memory");   // tile0 landed
        asm volatile("" ::: "memory");
        __builtin_amdgcn_s_barrier();
    }

    bf16x8 af  [4][2];   // A rows 0-63 of wave slab
    bf16x8 af2 [4][2];   // A rows 64-127 of wave slab
    bf16x8 bfr01[2][2];  // B cols wcb+0..31
    bf16x8 bfr23[2][2];  // B cols wcb+32..63

#pragma unroll
    for (int m = 0; m < 4; ++m) {
        af[m][0] = ldsfrag(&lds[0][0][0], wrb + m * 16 + rr, (rqb) ^ sw);
        af[m][1] = ldsfrag(&lds[0][0][0], wrb + m * 16 + rr, (64 + rqb) ^ sw);
    }
#pragma unroll
    for (int n = 0; n < 2; ++n) {
        bfr01[n][0] = ldsfrag(&lds[0][1][0], wcb + n * 16 + rr, (rqb) ^ sw);
        bfr01[n][1] = ldsfrag(&lds[0][1][0], wcb + n * 16 + rr, (64 + rqb) ^ sw);
    }

    for (int kt = 0; kt < NT; ++kt) {
        const int c = kt & 1;
        const unsigned short* At  = &lds[c][0][0];
        const unsigned short* Bt  = &lds[c][1][0];
        const unsigned short* nxA = &lds[c ^ 1][0][0];  // tile kt+1
        const unsigned short* nxB = &lds[c ^ 1][1][0];
        unsigned short* curA = &lds[c][0][0];           // tile kt+2 targets
        unsigned short* curB = &lds[c][1][0];
        const bool pf1 = (kt + 1 < NT);
        const bool pf2 = (kt + 2 < NT);

        // -- ph0: read b23(cur) + af2[0] (6); MFMA af x b01 ------------------
        PH_BAR();
#pragma unroll
        for (int n = 0; n < 2; ++n) {
            bfr23[n][0] = ldsfrag(Bt, wcb + 32 + n * 16 + rr, (rqb) ^ sw);
            bfr23[n][1] = ldsfrag(Bt, wcb + 32 + n * 16 + rr, (64 + rqb) ^ sw);
        }
        af2[0][0] = ldsfrag(At, wrb + 64 + rr, (rqb) ^ sw);
        af2[0][1] = ldsfrag(At, wrb + 64 + rr, (64 + rqb) ^ sw);
        LGKM(6);
        MFMA_Q(af, bfr01, 0, 0);

        // -- ph1: read af2[1-3] (6); MFMA af x b23; drain stages -------------
        PH_BAR();
#pragma unroll
        for (int m = 1; m < 4; ++m) {
            af2[m][0] = ldsfrag(At, wrb + 64 + m * 16 + rr, (rqb) ^ sw);
            af2[m][1] = ldsfrag(At, wrb + 64 + m * 16 + rr, (64 + rqb) ^ sw);
        }
        LGKM(8);
        MFMA_Q(af, bfr23, 0, 2);
        __builtin_amdgcn_sched_barrier(0);
        asm volatile("s_waitcnt vmcnt(0)" ::: "memory");  // tile kt+1 landed
        asm volatile("" ::: "memory");

        // -- ph2: stage B(kt+2); read af(kt+1)[0-2] (6); MFMA af2 x b01 ------
        PH_BAR();
        if (pf2) {
            stage_g(Bm, brow, kt + 2, 0, curB, t);
            stage_g(Bm, brow, kt + 2, 1, curB, t);
            stage_g(Bm, brow, kt + 2, 2, curB, t);
            stage_g(Bm, brow, kt + 2, 3, curB, t);
        }
        if (pf1) {
#pragma unroll
            for (int m = 0; m < 3; ++m) {
                af[m][0] = ldsfrag(nxA, wrb + m * 16 + rr, (rqb) ^ sw);
                af[m][1] = ldsfrag(nxA, wrb + m * 16 + rr, (64 + rqb) ^ sw);
            }
            LGKM(6);
        } else {
            LGKM(0);
        }
        MFMA_Q(af2, bfr01, 4, 0);

        // -- ph3: stage A(kt+2); read af[3] + b01(kt+1) (6); MFMA af2 x b23 --
        PH_BAR();
        if (pf2) {
            stage_g(A, arow, kt + 2, 0, curA, t);
            stage_g(A, arow, kt + 2, 1, curA, t);
            stage_g(A, arow, kt + 2, 2, curA, t);
            stage_g(A, arow, kt + 2, 3, curA, t);
        }
        if (pf1) {
            af[3][0] = ldsfrag(nxA, wrb + 48 + rr, (rqb) ^ sw);
            af[3][1] = ldsfrag(nxA, wrb + 48 + rr, (64 + rqb) ^ sw);
#pragma unroll
            for (int n = 0; n < 2; ++n) {
                bfr01[n][0] = ldsfrag(nxB, wcb + n * 16 + rr, (rqb) ^ sw);
                bfr01[n][1] = ldsfrag(nxB, wcb + n * 16 + rr, (64 + rqb) ^ sw);
            }
        }
        MFMA_Q(af2, bfr23, 4, 2);
    }

#pragma unroll
    for (int mi = 0; mi < 8; ++mi) {
#pragma unroll
        for (int n = 0; n < 4; ++n) {
            const int gcol = nblk * BN + wcb + n * 16 + rr;
#pragma unroll
            for (int j = 0; j < 4; ++j) {
                const int grow = mblk * BM + wrb + mi * 16 + rq * 4 + j;
                C[(size_t)grow * HIDDEN + gcol] = acc[mi][n][j];
            }
        }
    }
}

// ---------------------------------------------------------------------------
// In-place: p = C + MQ[idx[row]] + (W_b+U_b+Q_b); LayerNorm; sigmoid (R11).
// ---------------------------------------------------------------------------
__global__ __launch_bounds__(256) void ln_kernel(
        float* __restrict__ C,
        const int* __restrict__ idxbuf,
        const float* __restrict__ MQ,
        const float* __restrict__ W_b, const float* __restrict__ U_b,
        const float* __restrict__ Q_b, const float* __restrict__ ln_g,
        const float* __restrict__ ln_b) {
    const int row = blockIdx.x;
    const int t   = threadIdx.x;
    const int midx = idxbuf[row];
    float4* rowp = reinterpret_cast<float4*>(C + (size_t)row * HIDDEN);
    const float4* mqp = reinterpret_cast<const float4*>(MQ + (size_t)midx * HIDDEN);

    float4 p  = rowp[t];
    float4 mq = mqp[t];
    float4 bw = reinterpret_cast<const float4*>(W_b)[t];
    float4 bu = reinterpret_cast<const float4*>(U_b)[t];
    float4 bq = reinterpret_cast<const float4*>(Q_b)[t];
    p.x += mq.x + bw.x + bu.x + bq.x;
    p.y += mq.y + bw.y + bu.y + bq.y;
    p.z += mq.z + bw.z + bu.z + bq.z;
    p.w += mq.w + bw.w + bu.w + bq.w;

    float s  = p.x + p.y + p.z + p.w;
    float sq = p.x * p.x + p.y * p.y + p.z * p.z + p.w * p.w;
#pragma unroll
    for (int off = 32; off >= 1; off >>= 1) {
        s  += __shfl_xor(s,  off, 64);
        sq += __shfl_xor(sq, off, 64);
    }
    __shared__ float red[8];
    const int lane = t & 63, w = t >> 6;
    if (lane == 0) { red[w] = s; red[4 + w] = sq; }
    __syncthreads();
    const float S    = red[0] + red[1] + red[2] + red[3];
    const float SQ   = red[4] + red[5] + red[6] + red[7];
    const float mean = S * (1.0f / HIDDEN);
    const float var  = SQ * (1.0f / HIDDEN) - mean * mean;
    const float rstd = rsqrtf(var + 1e-5f);

    float4 g = reinterpret_cast<const float4*>(ln_g)[t];
    float4 b = reinterpret_cast<const float4*>(ln_b)[t];
    float4 o;
    o.x = 1.f / (1.f + __expf(-((p.x - mean) * rstd * g.x + b.x)));
    o.y = 1.f / (1.f + __expf(-((p.y - mean) * rstd * g.y + b.y)));
    o.z = 1.f / (1.f + __expf(-((p.z - mean) * rstd * g.z + b.z)));
    o.w = 1.f / (1.f + __expf(-((p.w - mean) * rstd * g.w + b.w)));
    rowp[t] = o;
}

// ---------------------------------------------------------------------------
extern "C" void kernel_launch(void* const* d_in, const int* in_sizes, int n_in,
                              void* d_out, int out_size, void* d_ws, size_t ws_size,
                              hipStream_t stream) {
    const float* x      = (const float*)d_in[0];
    const float* h_prev = (const float*)d_in[1];
    const float* memory = (const float*)d_in[2];
    const float* W_w    = (const float*)d_in[3];
    const float* W_b    = (const float*)d_in[4];
    const float* U_w    = (const float*)d_in[5];
    const float* U_b    = (const float*)d_in[6];
    const float* Q_w    = (const float*)d_in[7];
    const float* Q_b    = (const float*)d_in[8];
    const float* M_w    = (const float*)d_in[9];
    const float* M_b    = (const float*)d_in[10];
    const float* ln_g   = (const float*)d_in[11];
    const float* ln_b   = (const float*)d_in[12];

    // ws layout (bytes):
    char* ws = (char*)d_ws;
    unsigned short* A   = (unsigned short*)(ws);                 // 67,108,864
    unsigned short* Bm  = (unsigned short*)(ws + 67108864);      //  4,194,304
    float*          MQ  = (float*)         (ws + 71303168);      //  4,194,304
    int*            idx = (int*)           (ws + 75497472);      //     65,536

    float* pre = (float*)d_out;

    hipMemsetAsync(MQ, 0, (size_t)MEMSZ * HIDDEN * sizeof(float), stream);
    hipLaunchKernelGGL(front_kernel, dim3(BBLK + SBLK), dim3(256), 0, stream,
                       W_w, U_w, x, h_prev, M_w, M_b, Bm, A, idx);
    hipLaunchKernelGGL(gemm_mq_kernel,
                       dim3(MQB + (BATCH / BM) * (HIDDEN / BN)), dim3(512), 0, stream,
                       A, Bm, memory, Q_w, MQ, pre);
    hipLaunchKernelGGL(ln_kernel, dim3(BATCH), dim3(256), 0, stream,
                       pre, idx, MQ, W_b, U_b, Q_b, ln_g, ln_b);
}